// Round 9
// baseline (659.206 us; speedup 1.0000x reference)
//
#include <hip/hip_runtime.h>
#include <hip/hip_bf16.h>
#include <math.h>

#define LRELU 0.01f

// ---------- vectorized LDS weight fetch ----------
template<int CO_BLK>
__device__ __forceinline__ void ldw(const float* p, float* w) {
    if constexpr (CO_BLK % 4 == 0) {
#pragma unroll
        for (int u = 0; u < CO_BLK / 4; u++) {
            float4 v = *(const float4*)(p + 4 * u);
            w[4*u] = v.x; w[4*u+1] = v.y; w[4*u+2] = v.z; w[4*u+3] = v.w;
        }
    } else {
#pragma unroll
        for (int c = 0; c < CO_BLK; c++) w[c] = p[c];
    }
}

// ======================= fused prep: weights + cbnorm + loss zero ===========
__device__ __forceinline__ void wfwd(const float* s, float* d, int CIN, int COUT,
                                     int KK, int i) {
    int co = i / (CIN * KK); int r = i - co * CIN * KK;
    int ci = r / KK; int t = r - ci * KK;
    d[(ci * KK + t) * COUT + co] = s[i];
}
__device__ __forceinline__ void wtr(const float* s, float* d, int CIN, int COUT,
                                    int KK, int i) {
    int ci = i / (COUT * KK); int r = i - ci * COUT * KK;
    int co = r / KK; int t = r - co * KK;
    d[(t * CIN + ci) * COUT + co] = s[i];
}
__global__ __launch_bounds__(256)
void prep_k(const float* e1, const float* e2, const float* e3, const float* e4,
            const float* e5, const float* d1, const float* d2, const float* d3,
            const float* d4, float* w, const float* cbp, float* hcbn,
            float* loss) {
    int i = blockIdx.x * 256 + threadIdx.x;
    if      (i < 128)   wfwd(e1, w + 0,     1,  8, 16, i);
    else if (i < 2176)  wfwd(e2, w + 128,   8, 16, 16, i - 128);
    else if (i < 10368) wfwd(e3, w + 2176, 16, 32, 16, i - 2176);
    else if (i < 19584) wfwd(e4, w + 10368, 32, 32, 9, i - 10368);
    else if (i < 21632) wfwd(e5, w + 19584, 32, 64, 1, i - 19584);
    else if (i < 40064) wfwd(d1, w + 21632, 64, 32, 9, i - 21632);
    else if (i < 48256) wtr (d2, w + 40064, 32, 16, 16, i - 40064);
    else if (i < 50304) wtr (d3, w + 48256, 16,  8, 16, i - 48256);
    else if (i < 50432) wtr (d4, w + 50304,  8,  1, 16, i - 50304);
    else if (i < 50944) {
        int k = i - 50432;
        const float* c = cbp + k * 64;
        float s = 0.f;
#pragma unroll
        for (int d = 0; d < 64; d++) s = fmaf(c[d], c[d], s);
        hcbn[k] = 0.5f * s;
    } else if (i == 50944) {
        loss[0] = 0.f;
    }
}

// ======================= frame zeroing =======================
__global__ __launch_bounds__(256)
void zframes_k(float* a, float* zb) {
    int i = blockIdx.x * 256 + threadIdx.x;
    const int NA = 64 * 32 * 124;
    const int NZ = 64 * 64 * 124;
    float* p; int j;
    if (i < NA)           { p = a;  j = i; }
    else if (i < NA + NZ) { p = zb; j = i - NA; }
    else return;
    int pl = j / 124, s = j - pl * 124;
    int r, c;
    if (s < 32)      { r = 0;  c = s; }
    else if (s < 64) { r = 31; c = s - 32; }
    else { int u = s - 64; r = 1 + (u >> 1); c = (u & 1) * 31; }
    p[(size_t)pl * 1024 + r * 32 + c] = 0.f;
}
__global__ __launch_bounds__(256)
void zsides_k(float* d2o, float* d3o) {
    int i = blockIdx.x * 256 + threadIdx.x;
    const int N2 = 64 * 16 * 63 * 3;
    const int N3 = 64 * 8 * 129 * 3;
    if (i < N2) {
        int pl = i / 189, u = i - pl * 189;
        int r = u / 3, c3 = u - r * 3;
        int col = (c3 == 0) ? 0 : 63 + c3;
        d2o[((size_t)pl * 63 + r) * 66 + col] = 0.f;
    } else if (i < N2 + N3) {
        int j = i - N2;
        int pl = j / 387, u = j - pl * 387;
        int r = u / 3, c3 = u - r * 3;
        int col = (c3 == 0) ? 0 : 129 + c3;
        d3o[((size_t)pl * 129 + r) * 132 + col] = 0.f;
    }
}

// ======================= k4 s2 forward conv, LDS weights ====================
template<int CIN, int COUT, int CO_BLK, int HIN, int ISTR, int HOUT, int WOUT,
         int OPLANE, int OSTR, int OPAD, int CB, int RB>
__global__ __launch_bounds__(256)
void convs2_k(const float* __restrict__ in, const float* __restrict__ wt,
              const float* __restrict__ bias, float* __restrict__ out) {
    __shared__ __align__(16) float lw[CIN * 16 * CO_BLK];
    const int cog = blockIdx.y, b = blockIdx.z;
    for (int i = threadIdx.x; i < CIN * 16 * CO_BLK; i += 256) {
        int row = i / CO_BLK, c = i - row * CO_BLK;
        lw[i] = wt[row * COUT + cog * CO_BLK + c];
    }
    __syncthreads();

    const int bx = blockIdx.x;
    const int cbi = bx / RB, rb = bx - cbi * RB;
    const int tx = threadIdx.x & 15, ty = threadIdx.x >> 4;
    const int ow0 = (cbi * 16 + tx) * 2;
    const int oh  = rb * 16 + ty;
    if (oh >= HOUT || ow0 >= WOUT) return;
    const bool p1v = (ow0 + 1) < WOUT;

    float acc[CO_BLK][2];
#pragma unroll
    for (int c = 0; c < CO_BLK; c++) {
        float bv = bias[cog * CO_BLK + c];
        acc[c][0] = bv; acc[c][1] = bv;
    }
    const float* inb = in + ((size_t)(b * CIN) * HIN + oh * 2) * ISTR + ow0 * 2;
#pragma unroll 2
    for (int ci = 0; ci < CIN; ci++) {
        const float* r = inb + (size_t)ci * HIN * ISTR;
        float4 a4[4]; float2 b2[4];
#pragma unroll
        for (int kh = 0; kh < 4; kh++) {
            a4[kh] = *(const float4*)(r + kh * ISTR);
            b2[kh] = p1v ? *(const float2*)(r + kh * ISTR + 4) : make_float2(0.f, 0.f);
        }
        const float* wr = lw + ci * 16 * CO_BLK;
#pragma unroll
        for (int kh = 0; kh < 4; kh++) {
            float x0[4] = {a4[kh].x, a4[kh].y, a4[kh].z, a4[kh].w};
            float x1[4] = {a4[kh].z, a4[kh].w, b2[kh].x, b2[kh].y};
#pragma unroll
            for (int kw = 0; kw < 4; kw++) {
                float wv[CO_BLK];
                ldw<CO_BLK>(wr + (kh * 4 + kw) * CO_BLK, wv);
#pragma unroll
                for (int c = 0; c < CO_BLK; c++) {
                    acc[c][0] = fmaf(x0[kw], wv[c], acc[c][0]);
                    acc[c][1] = fmaf(x1[kw], wv[c], acc[c][1]);
                }
            }
        }
    }
    float* ob = out + (size_t)(b * COUT + cog * CO_BLK) * OPLANE
                    + (oh + OPAD) * OSTR + ow0 + OPAD;
#pragma unroll
    for (int c = 0; c < CO_BLK; c++) {
        float v0 = acc[c][0]; v0 = (v0 >= 0.f) ? v0 : LRELU * v0;
        ob[(size_t)c * OPLANE] = v0;
        if (p1v) {
            float v1 = acc[c][1]; v1 = (v1 >= 0.f) ? v1 : LRELU * v1;
            ob[(size_t)c * OPLANE + 1] = v1;
        }
    }
}

// ======================= k3 s1 p1 conv on padded [B,C,32,32], LDS weights ===
template<int CIN, int COUT, int CO_BLK, int OPLANE, int OSTR, int OPADH, int OPADV,
         bool ZSIDE>
__global__ __launch_bounds__(256)
void conv3_k(const float* __restrict__ in, const float* __restrict__ wt,
             const float* __restrict__ bias, float* __restrict__ out) {
    __shared__ __align__(16) float lw[CIN * 9 * CO_BLK];
    const int cog = blockIdx.y, b = blockIdx.z;
    for (int i = threadIdx.x; i < CIN * 9 * CO_BLK; i += 256) {
        int row = i / CO_BLK, c = i - row * CO_BLK;
        lw[i] = wt[row * COUT + cog * CO_BLK + c];
    }
    __syncthreads();

    const int rb = blockIdx.x;
    const int tx = threadIdx.x & 15, ty = threadIdx.x >> 4;
    const int r = rb * 16 + ty;
    if (r >= 30) return;
    const int ow0 = tx * 2;
    if (tx == 15) {
        if (ZSIDE) {
#pragma unroll
            for (int c = 0; c < CO_BLK; c++) {
                float* base = out + (size_t)(b * COUT + cog * CO_BLK + c) * OPLANE
                                  + (r + OPADV) * OSTR;
                base[0] = 0.f; base[31] = 0.f; base[32] = 0.f;
            }
        }
        return;
    }
    float acc[CO_BLK][2];
#pragma unroll
    for (int c = 0; c < CO_BLK; c++) {
        float bv = bias[cog * CO_BLK + c];
        acc[c][0] = bv; acc[c][1] = bv;
    }
    const float* inb = in + ((size_t)(b * CIN) * 32 + r) * 32 + ow0;
#pragma unroll 2
    for (int ci = 0; ci < CIN; ci++) {
        const float* rr = inb + (size_t)ci * 1024;
        float2 A[3], Bv[3];
#pragma unroll
        for (int kh = 0; kh < 3; kh++) {
            A[kh]  = *(const float2*)(rr + kh * 32);
            Bv[kh] = *(const float2*)(rr + kh * 32 + 2);
        }
        const float* wr = lw + ci * 9 * CO_BLK;
#pragma unroll
        for (int kh = 0; kh < 3; kh++) {
            float x0[3] = {A[kh].x, A[kh].y, Bv[kh].x};
            float x1[3] = {A[kh].y, Bv[kh].x, Bv[kh].y};
#pragma unroll
            for (int kw = 0; kw < 3; kw++) {
                float wv[CO_BLK];
                ldw<CO_BLK>(wr + (kh * 3 + kw) * CO_BLK, wv);
#pragma unroll
                for (int c = 0; c < CO_BLK; c++) {
                    acc[c][0] = fmaf(x0[kw], wv[c], acc[c][0]);
                    acc[c][1] = fmaf(x1[kw], wv[c], acc[c][1]);
                }
            }
        }
    }
    float* ob = out + (size_t)(b * COUT + cog * CO_BLK) * OPLANE
                    + (r + OPADV) * OSTR + ow0 + OPADH;
#pragma unroll
    for (int c = 0; c < CO_BLK; c++) {
        float v0 = acc[c][0]; v0 = (v0 >= 0.f) ? v0 : LRELU * v0;
        float v1 = acc[c][1]; v1 = (v1 >= 0.f) ? v1 : LRELU * v1;
        ob[(size_t)c * OPLANE] = v0;
        ob[(size_t)c * OPLANE + 1] = v1;
    }
}

// ======================= 1x1 conv on padded planes, LDS weights =============
template<int CIN, int COUT, int CO_BLK>
__global__ __launch_bounds__(256)
void conv1_k(const float* __restrict__ in, const float* __restrict__ wt,
             const float* __restrict__ bias, float* __restrict__ out) {
    __shared__ __align__(16) float lw[CIN * CO_BLK];
    const int cog = blockIdx.x, b = blockIdx.z;
    for (int i = threadIdx.x; i < CIN * CO_BLK; i += 256) {
        int row = i / CO_BLK, c = i - row * CO_BLK;
        lw[i] = wt[row * COUT + cog * CO_BLK + c];
    }
    __syncthreads();

    const int px4 = threadIdx.x * 4;
    float acc[CO_BLK][4];
#pragma unroll
    for (int c = 0; c < CO_BLK; c++) {
        float bv = bias[cog * CO_BLK + c];
        acc[c][0] = bv; acc[c][1] = bv; acc[c][2] = bv; acc[c][3] = bv;
    }
#pragma unroll 4
    for (int ci = 0; ci < CIN; ci++) {
        float4 x = *(const float4*)(in + (size_t)(b * CIN + ci) * 1024 + px4);
        float wv[CO_BLK];
        ldw<CO_BLK>(lw + ci * CO_BLK, wv);
#pragma unroll
        for (int c = 0; c < CO_BLK; c++) {
            acc[c][0] = fmaf(x.x, wv[c], acc[c][0]);
            acc[c][1] = fmaf(x.y, wv[c], acc[c][1]);
            acc[c][2] = fmaf(x.z, wv[c], acc[c][2]);
            acc[c][3] = fmaf(x.w, wv[c], acc[c][3]);
        }
    }
#pragma unroll
    for (int c = 0; c < CO_BLK; c++) {
        float4 v;
        v.x = (acc[c][0] >= 0.f) ? acc[c][0] : LRELU * acc[c][0];
        v.y = (acc[c][1] >= 0.f) ? acc[c][1] : LRELU * acc[c][1];
        v.z = (acc[c][2] >= 0.f) ? acc[c][2] : LRELU * acc[c][2];
        v.w = (acc[c][3] >= 0.f) ? acc[c][3] : LRELU * acc[c][3];
        *(float4*)(out + (size_t)(b * COUT + cog * CO_BLK + c) * 1024 + px4) = v;
    }
}

// ======================= convT k4 s2, parity classes, LDS weights ===========
template<int CIN, int COUT, int CO_BLK, int HIN, int ISTR, int HOUT, int WOUT,
         int OPLANE, int OSTR, int OPADH, int TX, int CB, int RB, bool DO_TANH>
__global__ __launch_bounds__(256)
void convt2_k(const float* __restrict__ in, const float* __restrict__ wt,
              const float* __restrict__ bias, float* __restrict__ out) {
    __shared__ __align__(16) float lw[4 * CIN * CO_BLK];  // [a*2+q][ci][c]
    const int x = blockIdx.x;
    const int cls = x / (CB * RB);
    const int rem = x - cls * (CB * RB);
    const int cb = rem / RB, rb = rem - cb * RB;
    const int py = cls & 1, px = cls >> 1;
    const int cog = blockIdx.y, b = blockIdx.z;

    for (int i = threadIdx.x; i < 4 * CIN * CO_BLK; i += 256) {
        int aq = i / (CIN * CO_BLK); int rr2 = i - aq * CIN * CO_BLK;
        int ci = rr2 / CO_BLK; int c = rr2 - ci * CO_BLK;
        int a = aq >> 1, q = aq & 1;
        int tap = (py + 2 * a) * 4 + px + 2 * q;
        lw[i] = wt[(tap * CIN + ci) * COUT + cog * CO_BLK + c];
    }
    __syncthreads();

    const int H2 = (HOUT - py + 1) >> 1;
    const int W2 = (WOUT - px + 1) >> 1;
    const int TY = 256 / TX;
    const int tx = threadIdx.x % TX, ty = threadIdx.x / TX;
    const int o0 = (cb * TX + tx) * 2;
    const int oh2 = rb * TY + ty;
    if (oh2 >= H2 || o0 >= W2) return;
    const bool p1v = (o0 + 1) < W2;

    float acc[CO_BLK][2];
#pragma unroll
    for (int c = 0; c < CO_BLK; c++) {
        float bv = bias[cog * CO_BLK + c];
        acc[c][0] = bv; acc[c][1] = bv;
    }
#pragma unroll
    for (int a = 0; a < 2; a++) {
        int ih = oh2 - a;
        bool rv = (ih >= 0) && (ih < HIN);
        const float* rowp = in + ((size_t)(b * CIN) * HIN + ih) * ISTR + o0;
        const float* lw0 = lw + (a * 2 + 0) * CIN * CO_BLK;
        const float* lw1 = lw + (a * 2 + 1) * CIN * CO_BLK;
#pragma unroll 2
        for (int ci = 0; ci < CIN; ci++) {
            const float* p = rowp + (size_t)ci * HIN * ISTR;
            float2 A  = rv ? *(const float2*)p : make_float2(0.f, 0.f);
            float2 Bv = (rv && p1v) ? *(const float2*)(p + 2) : make_float2(0.f, 0.f);
            float w0[CO_BLK], w1[CO_BLK];
            ldw<CO_BLK>(lw0 + ci * CO_BLK, w0);
            ldw<CO_BLK>(lw1 + ci * CO_BLK, w1);
#pragma unroll
            for (int c = 0; c < CO_BLK; c++) {
                acc[c][0] = fmaf(A.y, w0[c], acc[c][0]);
                acc[c][0] = fmaf(A.x, w1[c], acc[c][0]);
                acc[c][1] = fmaf(Bv.x, w0[c], acc[c][1]);
                acc[c][1] = fmaf(A.y, w1[c], acc[c][1]);
            }
        }
    }
    const int oh = 2 * oh2 + py, ow = 2 * o0 + px;
    float* ob = out + (size_t)(b * COUT + cog * CO_BLK) * OPLANE + oh * OSTR + ow + OPADH;
#pragma unroll
    for (int c = 0; c < CO_BLK; c++) {
        float v0 = acc[c][0];
        if (!DO_TANH) v0 = (v0 >= 0.f) ? v0 : LRELU * v0; else v0 = tanhf(v0);
        ob[(size_t)c * OPLANE] = v0;
        if (p1v) {
            float v1 = acc[c][1];
            if (!DO_TANH) v1 = (v1 >= 0.f) ? v1 : LRELU * v1; else v1 = tanhf(v1);
            ob[(size_t)c * OPLANE + 2] = v1;
        }
    }
}

// ======================= fused VQ: code-per-lane ============================
// 512 threads = 512 codes (row in VGPRs), 32 positions staged in LDS.
// Phase A: broadcast ds reads of position vec; each lane scores its code.
// Phase B: lanes 0..31 linear-scan 512 scores ascending (strict < => lowest
// index on tie, matching jnp.argmin). Epilogue: write z + loss. grid 1800.
__global__ __launch_bounds__(512)
void vq_k(const float* __restrict__ lat, const float* __restrict__ cb,
          const float* __restrict__ hcbn, float* __restrict__ z,
          float* __restrict__ loss_acc) {
    __shared__ __align__(16) float latb[32][68];
    __shared__ __align__(16) float sc[32][516];
    __shared__ int   sbidx[32];
    __shared__ float red[512];

    const int t = threadIdx.x;
    const int pos_l = t & 31, dgrp = t >> 5;       // dgrp 0..15
    const int pos = blockIdx.x * 32 + pos_l;
    const int b = pos / 900, p = pos - b * 900;
    const int oh = p / 30, ow = p - oh * 30;
    const int pp = 33 + oh * 32 + ow;
    const float* lb = lat + (size_t)b * 65536 + pp;

    // stage 32 position vectors
#pragma unroll
    for (int j = 0; j < 4; j++)
        latb[pos_l][dgrp * 4 + j] = lb[(size_t)(dgrp * 4 + j) * 1024];

    // this thread's code row -> VGPRs
    float c[64];
    {
        const float4* cr = (const float4*)(cb + (size_t)t * 64);
#pragma unroll
        for (int i = 0; i < 16; i++) {
            float4 v = cr[i];
            c[4*i] = v.x; c[4*i+1] = v.y; c[4*i+2] = v.z; c[4*i+3] = v.w;
        }
    }
    const float hn = hcbn[t];
    __syncthreads();

    // phase A: scores for all 32 positions vs my code
#pragma unroll 4
    for (int q = 0; q < 32; q++) {
        const float4* lp = (const float4*)(&latb[q][0]);
        float d0 = 0.f, d1 = 0.f, d2 = 0.f, d3 = 0.f;
#pragma unroll
        for (int i = 0; i < 4; i++) {
            float4 v0 = lp[i*4+0], v1 = lp[i*4+1], v2 = lp[i*4+2], v3 = lp[i*4+3];
            float* dp = (i == 0) ? &d0 : (i == 1) ? &d1 : (i == 2) ? &d2 : &d3;
            float dv = *dp;
            dv = fmaf(c[16*i+0],  v0.x, dv); dv = fmaf(c[16*i+1],  v0.y, dv);
            dv = fmaf(c[16*i+2],  v0.z, dv); dv = fmaf(c[16*i+3],  v0.w, dv);
            dv = fmaf(c[16*i+4],  v1.x, dv); dv = fmaf(c[16*i+5],  v1.y, dv);
            dv = fmaf(c[16*i+6],  v1.z, dv); dv = fmaf(c[16*i+7],  v1.w, dv);
            dv = fmaf(c[16*i+8],  v2.x, dv); dv = fmaf(c[16*i+9],  v2.y, dv);
            dv = fmaf(c[16*i+10], v2.z, dv); dv = fmaf(c[16*i+11], v2.w, dv);
            dv = fmaf(c[16*i+12], v3.x, dv); dv = fmaf(c[16*i+13], v3.y, dv);
            dv = fmaf(c[16*i+14], v3.z, dv); dv = fmaf(c[16*i+15], v3.w, dv);
            *dp = dv;
        }
        sc[q][t] = hn - ((d0 + d1) + (d2 + d3));
    }
    __syncthreads();

    // phase B: argmin per position (ascending scan, strict <)
    if (t < 32) {
        float best = 3.4e38f; int bi = 0;
        const float* srow = &sc[t][0];
        for (int k = 0; k < 512; k += 4) {
            float4 s4 = *(const float4*)(srow + k);
            if (s4.x < best) { best = s4.x; bi = k; }
            if (s4.y < best) { best = s4.y; bi = k + 1; }
            if (s4.z < best) { best = s4.z; bi = k + 2; }
            if (s4.w < best) { best = s4.w; bi = k + 3; }
        }
        sbidx[t] = bi;
    }
    __syncthreads();

    // epilogue: write z (padded layout) + loss
    const int bi = sbidx[pos_l];
    float4 cv = *(const float4*)(cb + (size_t)bi * 64 + dgrp * 4);
    float* zrow = z + (size_t)b * 65536 + pp;
    float m = 0.f;
    {
        float l0 = latb[pos_l][dgrp*4+0];
        float l1 = latb[pos_l][dgrp*4+1];
        float l2 = latb[pos_l][dgrp*4+2];
        float l3 = latb[pos_l][dgrp*4+3];
        zrow[(size_t)(dgrp*4+0) * 1024] = cv.x;
        zrow[(size_t)(dgrp*4+1) * 1024] = cv.y;
        zrow[(size_t)(dgrp*4+2) * 1024] = cv.z;
        zrow[(size_t)(dgrp*4+3) * 1024] = cv.w;
        float e0 = cv.x - l0, e1 = cv.y - l1, e2 = cv.z - l2, e3 = cv.w - l3;
        m = fmaf(e0, e0, m); m = fmaf(e1, e1, m);
        m = fmaf(e2, e2, m); m = fmaf(e3, e3, m);
    }
    red[t] = m;
    __syncthreads();
    for (int s = 256; s > 0; s >>= 1) {
        if (t < s) red[t] += red[t + s];
        __syncthreads();
    }
    if (t == 0) atomicAdd(loss_acc, red[0]);
}

__global__ void loss_final_k(const float* __restrict__ loss_acc,
                             float* __restrict__ out_last, float inv_n) {
    if (blockIdx.x == 0 && threadIdx.x == 0)
        out_last[0] = 1.25f * loss_acc[0] * inv_n;
}

static inline int nblk(long long total) { return (int)((total + 255) / 256); }

extern "C" void kernel_launch(void* const* d_in, const int* in_sizes, int n_in,
                              void* d_out, int out_size, void* d_ws, size_t ws_size,
                              hipStream_t stream) {
    const float* x   = (const float*)d_in[0];
    const float* ew1 = (const float*)d_in[1];  const float* eb1 = (const float*)d_in[2];
    const float* ew2 = (const float*)d_in[3];  const float* eb2 = (const float*)d_in[4];
    const float* ew3 = (const float*)d_in[5];  const float* eb3 = (const float*)d_in[6];
    const float* ew4 = (const float*)d_in[7];  const float* eb4 = (const float*)d_in[8];
    const float* ew5 = (const float*)d_in[9];  const float* eb5 = (const float*)d_in[10];
    const float* dw1 = (const float*)d_in[11]; const float* db1 = (const float*)d_in[12];
    const float* dw2 = (const float*)d_in[13]; const float* db2 = (const float*)d_in[14];
    const float* dw3 = (const float*)d_in[15]; const float* db3 = (const float*)d_in[16];
    const float* dw4 = (const float*)d_in[17]; const float* db4 = (const float*)d_in[18];
    const float* cb  = (const float*)d_in[19];
    float* out = (float*)d_out;

    const int B = in_sizes[0] / (256 * 256);   // 64
    const int N = B * 900;                     // 57600

    char* ws = (char*)d_ws;
    float* A  = (float*)(ws);
    float* Bb = (float*)(ws + 34873344);
    float* hcbn = (float*)(ws + 51904512);
    float* loss = (float*)(ws + 51906560);
    float* wtb  = (float*)(ws + 51906816);
    float* ew1t = wtb;          float* ew2t = wtb + 128;
    float* ew3t = wtb + 2176;   float* ew4t = wtb + 10368;
    float* ew5t = wtb + 19584;  float* dw1t = wtb + 21632;
    float* dw2t = wtb + 40064;  float* dw3t = wtb + 48256;
    float* dw4t = wtb + 50304;

    prep_k<<<nblk(50945), 256, 0, stream>>>(ew1, ew2, ew3, ew4, ew5,
                                            dw1, dw2, dw3, dw4, wtb,
                                            cb, hcbn, loss);

    // ---- encoder ----
    convs2_k<1, 8, 8, 256, 256, 127, 127, 127 * 128, 128, 0, 4, 8>
        <<<dim3(32, 1, B), 256, 0, stream>>>(x, ew1t, eb1, A);
    convs2_k<8, 16, 4, 127, 128, 62, 62, 62 * 64, 64, 0, 2, 4>
        <<<dim3(8, 4, B), 256, 0, stream>>>(A, ew2t, eb2, Bb);
    convs2_k<16, 32, 4, 62, 64, 30, 30, 1024, 32, 1, 1, 2>
        <<<dim3(2, 8, B), 256, 0, stream>>>(Bb, ew3t, eb3, A);
    zframes_k<<<nblk(64 * 32 * 124 + 64 * 64 * 124), 256, 0, stream>>>(A, Bb);
    conv3_k<32, 32, 4, 1024, 32, 1, 1, false>
        <<<dim3(2, 8, B), 256, 0, stream>>>(A, ew4t, eb4, Bb);
    conv1_k<32, 64, 4><<<dim3(16, 1, B), 256, 0, stream>>>(Bb, ew5t, eb5, A);

    // ---- fused VQ: lat=A -> z=Bb (+loss) ----
    vq_k<<<N / 32, 512, 0, stream>>>(A, cb, hcbn, Bb, loss);

    // ---- decoder ----
    conv3_k<64, 32, 4, 30 * 34, 34, 1, 0, true>
        <<<dim3(2, 8, B), 256, 0, stream>>>(Bb, dw1t, db1, A);
    convt2_k<32, 16, 4, 30, 34, 63, 63, 63 * 66, 66, 1, 16, 1, 2, false>
        <<<dim3(8, 4, B), 256, 0, stream>>>(A, dw2t, db2, Bb);
    zsides_k<<<nblk(64 * 16 * 63 * 3 + 64 * 8 * 129 * 3), 256, 0, stream>>>(Bb, A);
    convt2_k<16, 8, 8, 63, 66, 129, 129, 129 * 132, 132, 1, 32, 2, 9, false>
        <<<dim3(72, 1, B), 256, 0, stream>>>(Bb, dw3t, db3, A);
    convt2_k<8, 1, 1, 129, 132, 260, 260, 67600, 260, 0, 32, 3, 17, true>
        <<<dim3(204, 1, B), 256, 0, stream>>>(A, dw4t, db4, out);

    loss_final_k<<<1, 64, 0, stream>>>(loss, out + (out_size - 1),
                                       1.0f / ((float)N * 64.f));
}

// Round 10
// 499.476 us; speedup vs baseline: 1.3198x; 1.3198x over previous
//
#include <hip/hip_runtime.h>
#include <hip/hip_bf16.h>
#include <math.h>

#define LRELU 0.01f

// ---------- vectorized LDS weight fetch ----------
template<int CO_BLK>
__device__ __forceinline__ void ldw(const float* p, float* w) {
    if constexpr (CO_BLK % 4 == 0) {
#pragma unroll
        for (int u = 0; u < CO_BLK / 4; u++) {
            float4 v = *(const float4*)(p + 4 * u);
            w[4*u] = v.x; w[4*u+1] = v.y; w[4*u+2] = v.z; w[4*u+3] = v.w;
        }
    } else {
#pragma unroll
        for (int c = 0; c < CO_BLK; c++) w[c] = p[c];
    }
}

// ======================= fused prep =======================
__device__ __forceinline__ void wfwd(const float* s, float* d, int CIN, int COUT,
                                     int KK, int i) {
    int co = i / (CIN * KK); int r = i - co * CIN * KK;
    int ci = r / KK; int t = r - ci * KK;
    d[(ci * KK + t) * COUT + co] = s[i];
}
__device__ __forceinline__ void wtr(const float* s, float* d, int CIN, int COUT,
                                    int KK, int i) {
    int ci = i / (COUT * KK); int r = i - ci * COUT * KK;
    int co = r / KK; int t = r - co * KK;
    d[(t * CIN + ci) * COUT + co] = s[i];
}
__global__ __launch_bounds__(256)
void prep_k(const float* e1, const float* e2, const float* e3, const float* e4,
            const float* e5, const float* d1, const float* d2, const float* d3,
            const float* d4, float* w, const float* cbp, float* hcbn,
            unsigned long long* keys, float* loss, int N) {
    int i = blockIdx.x * 256 + threadIdx.x;
    if      (i < 128)   wfwd(e1, w + 0,     1,  8, 16, i);
    else if (i < 2176)  wfwd(e2, w + 128,   8, 16, 16, i - 128);
    else if (i < 10368) wfwd(e3, w + 2176, 16, 32, 16, i - 2176);
    else if (i < 19584) wfwd(e4, w + 10368, 32, 32, 9, i - 10368);
    else if (i < 21632) wfwd(e5, w + 19584, 32, 64, 1, i - 19584);
    else if (i < 40064) wfwd(d1, w + 21632, 64, 32, 9, i - 21632);
    else if (i < 48256) wtr (d2, w + 40064, 32, 16, 16, i - 40064);
    else if (i < 50304) wtr (d3, w + 48256, 16,  8, 16, i - 48256);
    else if (i < 50432) wtr (d4, w + 50304,  8,  1, 16, i - 50304);
    else if (i < 50944) {
        int k = i - 50432;
        const float* c = cbp + k * 64;
        float s = 0.f;
#pragma unroll
        for (int d = 0; d < 64; d++) s = fmaf(c[d], c[d], s);
        hcbn[k] = 0.5f * s;
    } else if (i < 50944 + N) {
        keys[i - 50944] = 0xFFFFFFFFFFFFFFFFull;
    } else if (i == 50944 + N) {
        loss[0] = 0.f;
    }
}

// ======================= frame zeroing =======================
__global__ __launch_bounds__(256)
void zframes_k(float* a, float* zb) {
    int i = blockIdx.x * 256 + threadIdx.x;
    const int NA = 64 * 32 * 124;
    const int NZ = 64 * 64 * 124;
    float* p; int j;
    if (i < NA)           { p = a;  j = i; }
    else if (i < NA + NZ) { p = zb; j = i - NA; }
    else return;
    int pl = j / 124, s = j - pl * 124;
    int r, c;
    if (s < 32)      { r = 0;  c = s; }
    else if (s < 64) { r = 31; c = s - 32; }
    else { int u = s - 64; r = 1 + (u >> 1); c = (u & 1) * 31; }
    p[(size_t)pl * 1024 + r * 32 + c] = 0.f;
}
__global__ __launch_bounds__(256)
void zsides_k(float* d2o, float* d3o) {
    int i = blockIdx.x * 256 + threadIdx.x;
    const int N2 = 64 * 16 * 63 * 3;
    const int N3 = 64 * 8 * 129 * 3;
    if (i < N2) {
        int pl = i / 189, u = i - pl * 189;
        int r = u / 3, c3 = u - r * 3;
        int col = (c3 == 0) ? 0 : 63 + c3;
        d2o[((size_t)pl * 63 + r) * 66 + col] = 0.f;
    } else if (i < N2 + N3) {
        int j = i - N2;
        int pl = j / 387, u = j - pl * 387;
        int r = u / 3, c3 = u - r * 3;
        int col = (c3 == 0) ? 0 : 129 + c3;
        d3o[((size_t)pl * 129 + r) * 132 + col] = 0.f;
    }
}

// ======================= k4 s2 forward conv =======================
// grid: (B=64 [x, XCD-co-located], cog [y], tile [z: cbi*RB+rb])
template<int CIN, int COUT, int CO_BLK, int HIN, int ISTR, int HOUT, int WOUT,
         int OPLANE, int OSTR, int OPAD, int CB, int RB>
__global__ __launch_bounds__(256)
void convs2_k(const float* __restrict__ in, const float* __restrict__ wt,
              const float* __restrict__ bias, float* __restrict__ out) {
    __shared__ __align__(16) float lw[CIN * 16 * CO_BLK];
    const int b = blockIdx.x, cog = blockIdx.y;
    for (int i = threadIdx.x; i < CIN * 16 * CO_BLK; i += 256) {
        int row = i / CO_BLK, c = i - row * CO_BLK;
        lw[i] = wt[row * COUT + cog * CO_BLK + c];
    }
    __syncthreads();

    const int tz = blockIdx.z;
    const int cbi = tz / RB, rb = tz - cbi * RB;
    const int tx = threadIdx.x & 15, ty = threadIdx.x >> 4;
    const int ow0 = (cbi * 16 + tx) * 2;
    const int oh  = rb * 16 + ty;
    if (oh >= HOUT || ow0 >= WOUT) return;
    const bool p1v = (ow0 + 1) < WOUT;

    float acc[CO_BLK][2];
#pragma unroll
    for (int c = 0; c < CO_BLK; c++) {
        float bv = bias[cog * CO_BLK + c];
        acc[c][0] = bv; acc[c][1] = bv;
    }
    const float* inb = in + ((size_t)(b * CIN) * HIN + oh * 2) * ISTR + ow0 * 2;
#pragma unroll 2
    for (int ci = 0; ci < CIN; ci++) {
        const float* r = inb + (size_t)ci * HIN * ISTR;
        float4 a4[4]; float2 b2[4];
#pragma unroll
        for (int kh = 0; kh < 4; kh++) {
            a4[kh] = *(const float4*)(r + kh * ISTR);
            b2[kh] = p1v ? *(const float2*)(r + kh * ISTR + 4) : make_float2(0.f, 0.f);
        }
        const float* wr = lw + ci * 16 * CO_BLK;
#pragma unroll
        for (int kh = 0; kh < 4; kh++) {
            float x0[4] = {a4[kh].x, a4[kh].y, a4[kh].z, a4[kh].w};
            float x1[4] = {a4[kh].z, a4[kh].w, b2[kh].x, b2[kh].y};
#pragma unroll
            for (int kw = 0; kw < 4; kw++) {
                float wv[CO_BLK];
                ldw<CO_BLK>(wr + (kh * 4 + kw) * CO_BLK, wv);
#pragma unroll
                for (int c = 0; c < CO_BLK; c++) {
                    acc[c][0] = fmaf(x0[kw], wv[c], acc[c][0]);
                    acc[c][1] = fmaf(x1[kw], wv[c], acc[c][1]);
                }
            }
        }
    }
    float* ob = out + (size_t)(b * COUT + cog * CO_BLK) * OPLANE
                    + (oh + OPAD) * OSTR + ow0 + OPAD;
#pragma unroll
    for (int c = 0; c < CO_BLK; c++) {
        float v0 = acc[c][0]; v0 = (v0 >= 0.f) ? v0 : LRELU * v0;
        ob[(size_t)c * OPLANE] = v0;
        if (p1v) {
            float v1 = acc[c][1]; v1 = (v1 >= 0.f) ? v1 : LRELU * v1;
            ob[(size_t)c * OPLANE + 1] = v1;
        }
    }
}

// ======================= k3 s1 p1 conv on padded [B,C,32,32] ================
// grid: (64 [x], cog [y], rb [z: 0..1])
template<int CIN, int COUT, int CO_BLK, int OPLANE, int OSTR, int OPADH, int OPADV,
         bool ZSIDE>
__global__ __launch_bounds__(256)
void conv3_k(const float* __restrict__ in, const float* __restrict__ wt,
             const float* __restrict__ bias, float* __restrict__ out) {
    __shared__ __align__(16) float lw[CIN * 9 * CO_BLK];
    const int b = blockIdx.x, cog = blockIdx.y;
    for (int i = threadIdx.x; i < CIN * 9 * CO_BLK; i += 256) {
        int row = i / CO_BLK, c = i - row * CO_BLK;
        lw[i] = wt[row * COUT + cog * CO_BLK + c];
    }
    __syncthreads();

    const int rb = blockIdx.z;
    const int tx = threadIdx.x & 15, ty = threadIdx.x >> 4;
    const int r = rb * 16 + ty;
    if (r >= 30) return;
    const int ow0 = tx * 2;
    if (tx == 15) {
        if (ZSIDE) {
#pragma unroll
            for (int c = 0; c < CO_BLK; c++) {
                float* base = out + (size_t)(b * COUT + cog * CO_BLK + c) * OPLANE
                                  + (r + OPADV) * OSTR;
                base[0] = 0.f; base[31] = 0.f; base[32] = 0.f;
            }
        }
        return;
    }
    float acc[CO_BLK][2];
#pragma unroll
    for (int c = 0; c < CO_BLK; c++) {
        float bv = bias[cog * CO_BLK + c];
        acc[c][0] = bv; acc[c][1] = bv;
    }
    const float* inb = in + ((size_t)(b * CIN) * 32 + r) * 32 + ow0;
#pragma unroll 2
    for (int ci = 0; ci < CIN; ci++) {
        const float* rr = inb + (size_t)ci * 1024;
        float2 A[3], Bv[3];
#pragma unroll
        for (int kh = 0; kh < 3; kh++) {
            A[kh]  = *(const float2*)(rr + kh * 32);
            Bv[kh] = *(const float2*)(rr + kh * 32 + 2);
        }
        const float* wr = lw + ci * 9 * CO_BLK;
#pragma unroll
        for (int kh = 0; kh < 3; kh++) {
            float x0[3] = {A[kh].x, A[kh].y, Bv[kh].x};
            float x1[3] = {A[kh].y, Bv[kh].x, Bv[kh].y};
#pragma unroll
            for (int kw = 0; kw < 3; kw++) {
                float wv[CO_BLK];
                ldw<CO_BLK>(wr + (kh * 3 + kw) * CO_BLK, wv);
#pragma unroll
                for (int c = 0; c < CO_BLK; c++) {
                    acc[c][0] = fmaf(x0[kw], wv[c], acc[c][0]);
                    acc[c][1] = fmaf(x1[kw], wv[c], acc[c][1]);
                }
            }
        }
    }
    float* ob = out + (size_t)(b * COUT + cog * CO_BLK) * OPLANE
                    + (r + OPADV) * OSTR + ow0 + OPADH;
#pragma unroll
    for (int c = 0; c < CO_BLK; c++) {
        float v0 = acc[c][0]; v0 = (v0 >= 0.f) ? v0 : LRELU * v0;
        float v1 = acc[c][1]; v1 = (v1 >= 0.f) ? v1 : LRELU * v1;
        ob[(size_t)c * OPLANE] = v0;
        ob[(size_t)c * OPLANE + 1] = v1;
    }
}

// ======================= 1x1 conv, grid (64 [x], cog [y], 1) ================
template<int CIN, int COUT, int CO_BLK>
__global__ __launch_bounds__(256)
void conv1_k(const float* __restrict__ in, const float* __restrict__ wt,
             const float* __restrict__ bias, float* __restrict__ out) {
    __shared__ __align__(16) float lw[CIN * CO_BLK];
    const int b = blockIdx.x, cog = blockIdx.y;
    for (int i = threadIdx.x; i < CIN * CO_BLK; i += 256) {
        int row = i / CO_BLK, c = i - row * CO_BLK;
        lw[i] = wt[row * COUT + cog * CO_BLK + c];
    }
    __syncthreads();

    const int px4 = threadIdx.x * 4;
    float acc[CO_BLK][4];
#pragma unroll
    for (int c = 0; c < CO_BLK; c++) {
        float bv = bias[cog * CO_BLK + c];
        acc[c][0] = bv; acc[c][1] = bv; acc[c][2] = bv; acc[c][3] = bv;
    }
#pragma unroll 4
    for (int ci = 0; ci < CIN; ci++) {
        float4 x = *(const float4*)(in + (size_t)(b * CIN + ci) * 1024 + px4);
        float wv[CO_BLK];
        ldw<CO_BLK>(lw + ci * CO_BLK, wv);
#pragma unroll
        for (int c = 0; c < CO_BLK; c++) {
            acc[c][0] = fmaf(x.x, wv[c], acc[c][0]);
            acc[c][1] = fmaf(x.y, wv[c], acc[c][1]);
            acc[c][2] = fmaf(x.z, wv[c], acc[c][2]);
            acc[c][3] = fmaf(x.w, wv[c], acc[c][3]);
        }
    }
#pragma unroll
    for (int c = 0; c < CO_BLK; c++) {
        float4 v;
        v.x = (acc[c][0] >= 0.f) ? acc[c][0] : LRELU * acc[c][0];
        v.y = (acc[c][1] >= 0.f) ? acc[c][1] : LRELU * acc[c][1];
        v.z = (acc[c][2] >= 0.f) ? acc[c][2] : LRELU * acc[c][2];
        v.w = (acc[c][3] >= 0.f) ? acc[c][3] : LRELU * acc[c][3];
        *(float4*)(out + (size_t)(b * COUT + cog * CO_BLK + c) * 1024 + px4) = v;
    }
}

// ======================= convT k4 s2 =======================
// grid: (64 [x], cog [y], cls*CB*RB [z])
template<int CIN, int COUT, int CO_BLK, int HIN, int ISTR, int HOUT, int WOUT,
         int OPLANE, int OSTR, int OPADH, int TX, int CB, int RB, bool DO_TANH>
__global__ __launch_bounds__(256)
void convt2_k(const float* __restrict__ in, const float* __restrict__ wt,
              const float* __restrict__ bias, float* __restrict__ out) {
    __shared__ __align__(16) float lw[4 * CIN * CO_BLK];
    const int b = blockIdx.x, cog = blockIdx.y;
    const int tz = blockIdx.z;
    const int cls = tz / (CB * RB);
    const int rem = tz - cls * (CB * RB);
    const int cb = rem / RB, rb = rem - cb * RB;
    const int py = cls & 1, px = cls >> 1;

    for (int i = threadIdx.x; i < 4 * CIN * CO_BLK; i += 256) {
        int aq = i / (CIN * CO_BLK); int rr2 = i - aq * CIN * CO_BLK;
        int ci = rr2 / CO_BLK; int c = rr2 - ci * CO_BLK;
        int a = aq >> 1, q = aq & 1;
        int tap = (py + 2 * a) * 4 + px + 2 * q;
        lw[i] = wt[(tap * CIN + ci) * COUT + cog * CO_BLK + c];
    }
    __syncthreads();

    const int H2 = (HOUT - py + 1) >> 1;
    const int W2 = (WOUT - px + 1) >> 1;
    const int TY = 256 / TX;
    const int tx = threadIdx.x % TX, ty = threadIdx.x / TX;
    const int o0 = (cb * TX + tx) * 2;
    const int oh2 = rb * TY + ty;
    if (oh2 >= H2 || o0 >= W2) return;
    const bool p1v = (o0 + 1) < W2;

    float acc[CO_BLK][2];
#pragma unroll
    for (int c = 0; c < CO_BLK; c++) {
        float bv = bias[cog * CO_BLK + c];
        acc[c][0] = bv; acc[c][1] = bv;
    }
#pragma unroll
    for (int a = 0; a < 2; a++) {
        int ih = oh2 - a;
        bool rv = (ih >= 0) && (ih < HIN);
        const float* rowp = in + ((size_t)(b * CIN) * HIN + ih) * ISTR + o0;
        const float* lw0 = lw + (a * 2 + 0) * CIN * CO_BLK;
        const float* lw1 = lw + (a * 2 + 1) * CIN * CO_BLK;
#pragma unroll 2
        for (int ci = 0; ci < CIN; ci++) {
            const float* p = rowp + (size_t)ci * HIN * ISTR;
            float2 A  = rv ? *(const float2*)p : make_float2(0.f, 0.f);
            float2 Bv = (rv && p1v) ? *(const float2*)(p + 2) : make_float2(0.f, 0.f);
            float w0[CO_BLK], w1[CO_BLK];
            ldw<CO_BLK>(lw0 + ci * CO_BLK, w0);
            ldw<CO_BLK>(lw1 + ci * CO_BLK, w1);
#pragma unroll
            for (int c = 0; c < CO_BLK; c++) {
                acc[c][0] = fmaf(A.y, w0[c], acc[c][0]);
                acc[c][0] = fmaf(A.x, w1[c], acc[c][0]);
                acc[c][1] = fmaf(Bv.x, w0[c], acc[c][1]);
                acc[c][1] = fmaf(A.y, w1[c], acc[c][1]);
            }
        }
    }
    const int oh = 2 * oh2 + py, ow = 2 * o0 + px;
    float* ob = out + (size_t)(b * COUT + cog * CO_BLK) * OPLANE + oh * OSTR + ow + OPADH;
#pragma unroll
    for (int c = 0; c < CO_BLK; c++) {
        float v0 = acc[c][0];
        if (!DO_TANH) v0 = (v0 >= 0.f) ? v0 : LRELU * v0; else v0 = tanhf(v0);
        ob[(size_t)c * OPLANE] = v0;
        if (p1v) {
            float v1 = acc[c][1];
            if (!DO_TANH) v1 = (v1 >= 0.f) ? v1 : LRELU * v1; else v1 = tanhf(v1);
            ob[(size_t)c * OPLANE + 2] = v1;
        }
    }
}

// ======================= VQ stage 1 (R7 structure + XCD swizzle) ============
// grid (232, 8): x = pos-block (225 real, co-located mod 8), y = 64-code eighth.
__global__ __launch_bounds__(256)
void vq_argmin_k(const float* __restrict__ lat, const float* __restrict__ cb,
                 const float* __restrict__ hcbn,
                 unsigned long long* __restrict__ keys) {
    const int pb = blockIdx.x;
    if (pb >= 225) return;
    __shared__ float4 scb4[1024];
    __shared__ float  shn[64];
    const int tid = threadIdx.x;
    const int dq  = tid & 3;
    const int pg  = tid >> 2;
    const int kbase = blockIdx.y * 64;
    const int posbase = pb * 256;

    const float4* src = (const float4*)(cb + (size_t)kbase * 64);
#pragma unroll
    for (int i = 0; i < 4; i++) scb4[tid + 256 * i] = src[tid + 256 * i];
    if (tid < 64) shn[tid] = hcbn[kbase + tid];

    float l[4][16];
    int   pidx[4];
#pragma unroll
    for (int j = 0; j < 4; j++) {
        int pos = posbase + pg + 64 * j;
        pidx[j] = pos;
        int b = pos / 900, p = pos - b * 900;
        int oh = p / 30, ow = p - oh * 30;
        int pp = 33 + oh * 32 + ow;
        const float* lb = lat + ((size_t)b * 64 + dq * 16) * 1024 + pp;
#pragma unroll
        for (int i = 0; i < 16; i++) l[j][i] = lb[i * 1024];
    }
    __syncthreads();

    float best[4] = {3.4e38f, 3.4e38f, 3.4e38f, 3.4e38f};
    int   bi[4]   = {0, 0, 0, 0};

#pragma unroll 2
    for (int k0 = 0; k0 < 64; k0++) {
        float4 c0 = scb4[k0 * 16 + dq * 4 + 0];
        float4 c1 = scb4[k0 * 16 + dq * 4 + 1];
        float4 c2 = scb4[k0 * 16 + dq * 4 + 2];
        float4 c3 = scb4[k0 * 16 + dq * 4 + 3];
        float hn = shn[k0];
#pragma unroll
        for (int j = 0; j < 4; j++) {
            float dot = 0.f;
            dot = fmaf(l[j][0],  c0.x, dot); dot = fmaf(l[j][1],  c0.y, dot);
            dot = fmaf(l[j][2],  c0.z, dot); dot = fmaf(l[j][3],  c0.w, dot);
            dot = fmaf(l[j][4],  c1.x, dot); dot = fmaf(l[j][5],  c1.y, dot);
            dot = fmaf(l[j][6],  c1.z, dot); dot = fmaf(l[j][7],  c1.w, dot);
            dot = fmaf(l[j][8],  c2.x, dot); dot = fmaf(l[j][9],  c2.y, dot);
            dot = fmaf(l[j][10], c2.z, dot); dot = fmaf(l[j][11], c2.w, dot);
            dot = fmaf(l[j][12], c3.x, dot); dot = fmaf(l[j][13], c3.y, dot);
            dot = fmaf(l[j][14], c3.z, dot); dot = fmaf(l[j][15], c3.w, dot);
            float full = dot + __shfl_xor(dot, 1);
            full += __shfl_xor(full, 2);
            float score = hn - full;
            if (score < best[j]) { best[j] = score; bi[j] = kbase + k0; }
        }
    }

    if (dq == 0) {
#pragma unroll
        for (int j = 0; j < 4; j++) {
            unsigned u = __float_as_uint(best[j]);
            u = ((int)u < 0) ? ~u : (u | 0x80000000u);
            unsigned long long key = ((unsigned long long)u << 32) | (unsigned)bi[j];
            atomicMin(&keys[pidx[j]], key);
        }
    }
}

// ======================= VQ stage 2 =======================
__global__ __launch_bounds__(256)
void vq_finalize_k(const float* __restrict__ lat, const float* __restrict__ cb,
                   const unsigned long long* __restrict__ keys,
                   float* __restrict__ z, float* __restrict__ loss_acc, int B) {
    int gid = blockIdx.x * 256 + threadIdx.x;
    const int N = B * 900;
    float myloss = 0.f;
    if (gid < N) {
        int b = gid / 900, p = gid - b * 900;
        int oh = p / 30, ow = p - oh * 30;
        int pp = 33 + oh * 32 + ow;
        int idx = (int)(unsigned)(keys[gid] & 0xFFFFFFFFull);
        const float4* crow = (const float4*)(cb + (size_t)idx * 64);
        const float* lrow = lat + (size_t)b * 64 * 1024 + pp;
        float*       zrow = z   + (size_t)b * 64 * 1024 + pp;
#pragma unroll
        for (int i = 0; i < 16; i++) {
            float4 cv = crow[i];
            float lv0 = lrow[(4 * i + 0) * 1024];
            float lv1 = lrow[(4 * i + 1) * 1024];
            float lv2 = lrow[(4 * i + 2) * 1024];
            float lv3 = lrow[(4 * i + 3) * 1024];
            zrow[(4 * i + 0) * 1024] = cv.x;
            zrow[(4 * i + 1) * 1024] = cv.y;
            zrow[(4 * i + 2) * 1024] = cv.z;
            zrow[(4 * i + 3) * 1024] = cv.w;
            float dd0 = cv.x - lv0, dd1 = cv.y - lv1, dd2 = cv.z - lv2, dd3 = cv.w - lv3;
            myloss = fmaf(dd0, dd0, myloss);
            myloss = fmaf(dd1, dd1, myloss);
            myloss = fmaf(dd2, dd2, myloss);
            myloss = fmaf(dd3, dd3, myloss);
        }
    }
    __shared__ float red[256];
    red[threadIdx.x] = myloss;
    __syncthreads();
    for (int s = 128; s > 0; s >>= 1) {
        if ((int)threadIdx.x < s) red[threadIdx.x] += red[threadIdx.x + s];
        __syncthreads();
    }
    if (threadIdx.x == 0) atomicAdd(loss_acc, red[0]);
}

__global__ void loss_final_k(const float* __restrict__ loss_acc,
                             float* __restrict__ out_last, float inv_n) {
    if (blockIdx.x == 0 && threadIdx.x == 0)
        out_last[0] = 1.25f * loss_acc[0] * inv_n;
}

static inline int nblk(long long total) { return (int)((total + 255) / 256); }

extern "C" void kernel_launch(void* const* d_in, const int* in_sizes, int n_in,
                              void* d_out, int out_size, void* d_ws, size_t ws_size,
                              hipStream_t stream) {
    const float* x   = (const float*)d_in[0];
    const float* ew1 = (const float*)d_in[1];  const float* eb1 = (const float*)d_in[2];
    const float* ew2 = (const float*)d_in[3];  const float* eb2 = (const float*)d_in[4];
    const float* ew3 = (const float*)d_in[5];  const float* eb3 = (const float*)d_in[6];
    const float* ew4 = (const float*)d_in[7];  const float* eb4 = (const float*)d_in[8];
    const float* ew5 = (const float*)d_in[9];  const float* eb5 = (const float*)d_in[10];
    const float* dw1 = (const float*)d_in[11]; const float* db1 = (const float*)d_in[12];
    const float* dw2 = (const float*)d_in[13]; const float* db2 = (const float*)d_in[14];
    const float* dw3 = (const float*)d_in[15]; const float* db3 = (const float*)d_in[16];
    const float* dw4 = (const float*)d_in[17]; const float* db4 = (const float*)d_in[18];
    const float* cb  = (const float*)d_in[19];
    float* out = (float*)d_out;

    const int B = in_sizes[0] / (256 * 256);   // 64
    const int N = B * 900;                     // 57600

    char* ws = (char*)d_ws;
    float* A  = (float*)(ws);
    float* Bb = (float*)(ws + 34873344);
    unsigned long long* keys = (unsigned long long*)(ws + 51904512);
    float* hcbn = (float*)(ws + 52365312);
    float* loss = (float*)(ws + 52367360);
    float* wtb  = (float*)(ws + 52367616);
    float* ew1t = wtb;          float* ew2t = wtb + 128;
    float* ew3t = wtb + 2176;   float* ew4t = wtb + 10368;
    float* ew5t = wtb + 19584;  float* dw1t = wtb + 21632;
    float* dw2t = wtb + 40064;  float* dw3t = wtb + 48256;
    float* dw4t = wtb + 50304;

    prep_k<<<nblk(50945 + N), 256, 0, stream>>>(ew1, ew2, ew3, ew4, ew5,
                                                dw1, dw2, dw3, dw4, wtb,
                                                cb, hcbn, keys, loss, N);

    // ---- encoder (grid.x = B for XCD co-location) ----
    convs2_k<1, 8, 8, 256, 256, 127, 127, 127 * 128, 128, 0, 4, 8>
        <<<dim3(B, 1, 32), 256, 0, stream>>>(x, ew1t, eb1, A);
    convs2_k<8, 16, 4, 127, 128, 62, 62, 62 * 64, 64, 0, 2, 4>
        <<<dim3(B, 4, 8), 256, 0, stream>>>(A, ew2t, eb2, Bb);
    convs2_k<16, 32, 4, 62, 64, 30, 30, 1024, 32, 1, 1, 2>
        <<<dim3(B, 8, 2), 256, 0, stream>>>(Bb, ew3t, eb3, A);
    zframes_k<<<nblk(64 * 32 * 124 + 64 * 64 * 124), 256, 0, stream>>>(A, Bb);
    conv3_k<32, 32, 4, 1024, 32, 1, 1, false>
        <<<dim3(B, 8, 2), 256, 0, stream>>>(A, ew4t, eb4, Bb);
    conv1_k<32, 64, 4><<<dim3(B, 16, 1), 256, 0, stream>>>(Bb, ew5t, eb5, A);

    // ---- VQ: lat=A -> keys -> z=Bb ----
    vq_argmin_k<<<dim3(232, 8), 256, 0, stream>>>(A, cb, hcbn, keys);
    vq_finalize_k<<<nblk(N), 256, 0, stream>>>(A, cb, keys, Bb, loss, B);

    // ---- decoder ----
    conv3_k<64, 32, 4, 30 * 34, 34, 1, 0, true>
        <<<dim3(B, 8, 2), 256, 0, stream>>>(Bb, dw1t, db1, A);
    convt2_k<32, 16, 4, 30, 34, 63, 63, 63 * 66, 66, 1, 16, 1, 2, false>
        <<<dim3(B, 4, 8), 256, 0, stream>>>(A, dw2t, db2, Bb);
    zsides_k<<<nblk(64 * 16 * 63 * 3 + 64 * 8 * 129 * 3), 256, 0, stream>>>(Bb, A);
    convt2_k<16, 8, 8, 63, 66, 129, 129, 129 * 132, 132, 1, 32, 2, 9, false>
        <<<dim3(B, 1, 72), 256, 0, stream>>>(Bb, dw3t, db3, A);
    convt2_k<8, 1, 1, 129, 132, 260, 260, 67600, 260, 0, 32, 3, 17, true>
        <<<dim3(B, 1, 204), 256, 0, stream>>>(A, dw4t, db4, out);

    loss_final_k<<<1, 64, 0, stream>>>(loss, out + (out_size - 1),
                                       1.0f / ((float)N * 64.f));
}